// Round 2
// baseline (1379.389 us; speedup 1.0000x reference)
//
#include <hip/hip_runtime.h>
#include <math.h>

#define NB 4
#define NC 12
#define NM 2
#define NN 320
#define NHW (NN*NN)
#define NBC (NB*NC)
#define CG_TOL 1e-6f
#define NITER 10
#define CBLK 400   // blocks per batch for combine/update kernels (102400/256)

#define PI_F     3.14159265358979323846f
#define TWO_PI_F 6.28318530717958647692f

typedef float2 c32;

__device__ __forceinline__ c32 cmul(c32 a, c32 b){ return make_float2(a.x*b.x - a.y*b.y, a.x*b.y + a.y*b.x); }
__device__ __forceinline__ c32 cmulj(c32 a, c32 b){ return make_float2(a.x*b.x + a.y*b.y, a.x*b.y - a.y*b.x); } // conj(a)*b
__device__ __forceinline__ c32 cadd(c32 a, c32 b){ return make_float2(a.x+b.x, a.y+b.y); }
__device__ __forceinline__ c32 csub(c32 a, c32 b){ return make_float2(a.x-b.x, a.y-b.y); }
__device__ __forceinline__ c32 cscale(c32 a, float s){ return make_float2(a.x*s, a.y*s); }

__device__ __forceinline__ float wave_reduce_f(float v) {
  #pragma unroll
  for (int off = 32; off >= 1; off >>= 1) v += __shfl_xor(v, off, 64);
  return v;
}
__device__ __forceinline__ c32 wave_reduce_c(c32 v) {
  #pragma unroll
  for (int off = 32; off >= 1; off >>= 1) {
    v.x += __shfl_xor(v.x, off, 64);
    v.y += __shfl_xor(v.y, off, 64);
  }
  return v;
}

// Build twiddle tables once per call; also zero the last-block counters.
// T320[j] = cis(2*pi*j/320), j=0..255 ; T64[k] = cis(2*pi*k/64), k=0..31.
__global__ __launch_bounds__(256)
void twiddle_init(c32* __restrict__ T320, c32* __restrict__ T64, unsigned* __restrict__ cnt)
{
  const int t = threadIdx.x;
  {
    float s, c; sincosf(TWO_PI_F * (float)t / 320.f, &s, &c);
    T320[t] = make_float2(c, s);
  }
  if (t < 32) {
    float s, c; sincosf(TWO_PI_F * (float)t / 64.f, &s, &c);
    T64[t] = make_float2(c, s);
  }
  if (t < 8) cnt[t] = 0u;
}

// 320-point FFT: A[j] = x[64*j + lane]; output A[k1] at lane l = X[k1 + 5*rev6(l)].
// ct[4] = cis(DIR*2pi*k*lane/320), tw[6] = stage twiddles (pre-signed). Unnormalized.
template<int DIR>
__device__ __forceinline__ void fft320_tw(c32 A[5], const c32 ct[4], const c32 tw[6], int lane)
{
  constexpr float C72  = 0.30901699437494745f, S72  = 0.9510565162951535f;
  constexpr float C144 = -0.8090169943749475f, S144 = 0.5877852522924731f;
  const float sgn = (float)DIR;
  const c32 w51 = make_float2(C72,  sgn*S72);
  const c32 w52 = make_float2(C144, sgn*S144);
  const c32 w53 = make_float2(C144, -sgn*S144);
  const c32 w54 = make_float2(C72,  -sgn*S72);
  c32 v0=A[0], v1=A[1], v2=A[2], v3=A[3], v4=A[4];
  A[0] = cadd(cadd(v0, v1), cadd(cadd(v2, v3), v4));
  A[1] = cadd(v0, cadd(cadd(cmul(v1,w51), cmul(v2,w52)), cadd(cmul(v3,w53), cmul(v4,w54))));
  A[2] = cadd(v0, cadd(cadd(cmul(v1,w52), cmul(v2,w54)), cadd(cmul(v3,w51), cmul(v4,w53))));
  A[3] = cadd(v0, cadd(cadd(cmul(v1,w53), cmul(v2,w51)), cadd(cmul(v3,w54), cmul(v4,w52))));
  A[4] = cadd(v0, cadd(cadd(cmul(v1,w54), cmul(v2,w53)), cadd(cmul(v3,w52), cmul(v4,w51))));
  A[1] = cmul(A[1], ct[0]);
  A[2] = cmul(A[2], ct[1]);
  A[3] = cmul(A[3], ct[2]);
  A[4] = cmul(A[4], ct[3]);
  #pragma unroll
  for (int s = 0; s < 6; ++s) {
    const int m = 32 >> s;
    const c32 w = tw[s];
    const bool up = (lane & m) != 0;
    #pragma unroll
    for (int k1 = 0; k1 < 5; ++k1) {
      c32 o;
      o.x = __shfl_xor(A[k1].x, m, 64);
      o.y = __shfl_xor(A[k1].y, m, 64);
      c32 lo = cadd(A[k1], o);
      c32 hi = cmul(csub(o, A[k1]), w);
      A[k1] = up ? hi : lo;
    }
  }
}

// One batched-1D-FFT pass over contiguous dim of (NBC, NN, NN), transposed write.
// IN_MODE: 0 = in[]; 1 = sum_m p*sm on the fly; 2 = in[]*mask.  OUT_MASK: *mask at write.
template<int DIR, int IN_MODE, int OUT_MASK>
__global__ __launch_bounds__(256)
void fft_pass(const c32* __restrict__ in, c32* __restrict__ out,
              const c32* __restrict__ pvec, const c32* __restrict__ smaps,
              const float* __restrict__ mask, const float* __restrict__ flag,
              const c32* __restrict__ T320, const c32* __restrict__ T64)
{
  if (flag != nullptr && flag[0] == 0.f) return;
  __shared__ c32 tile[8][NN + 2];   // stride 322: 2*322 % 32 == 4 -> ~2-way max on reads
  const int tid  = threadIdx.x;
  const int lane = tid & 63;
  const int wv   = tid >> 6;
  const int bc   = blockIdx.y;
  const int r0   = blockIdx.x * 8;
  const float sgn = (float)DIR;

  // hoisted lane-only twiddles (L1-resident tables)
  c32 ct[4], tw[6];
  #pragma unroll
  for (int k = 0; k < 4; ++k) {
    c32 t = T320[(k + 1) * lane];
    ct[k] = make_float2(t.x, sgn * t.y);
  }
  #pragma unroll
  for (int s = 0; s < 6; ++s) {
    const int m = 32 >> s;
    c32 t = T64[(lane & (m - 1)) << s];
    tw[s] = make_float2(t.x, sgn * t.y);
  }
  const int rv6 = __brev((unsigned)lane) >> 26;

  #pragma unroll
  for (int rep = 0; rep < 2; ++rep) {
    const int ri  = wv * 2 + rep;
    const int row = r0 + ri;
    c32 A[5];
    if constexpr (IN_MODE == 0) {
      #pragma unroll
      for (int j = 0; j < 5; ++j)
        A[j] = in[((size_t)bc * NN + row) * NN + lane + 64*j];
    } else if constexpr (IN_MODE == 1) {
      const int b = bc / NC;
      const int c = bc % NC;
      #pragma unroll
      for (int j = 0; j < 5; ++j) {
        const int col = lane + 64*j;
        const size_t hw = (size_t)row * NN + col;
        c32 p0 = pvec[(size_t)(b*NM + 0) * NHW + hw];
        c32 p1 = pvec[(size_t)(b*NM + 1) * NHW + hw];
        c32 s0 = smaps[(size_t)((b*NC + c)*NM + 0) * NHW + hw];
        c32 s1 = smaps[(size_t)((b*NC + c)*NM + 1) * NHW + hw];
        A[j] = cadd(cmul(p0, s0), cmul(p1, s1));
      }
    } else {
      #pragma unroll
      for (int j = 0; j < 5; ++j) {
        const size_t idx = ((size_t)bc * NN + row) * NN + lane + 64*j;
        A[j] = cscale(in[idx], mask[idx]);
      }
    }
    fft320_tw<DIR>(A, ct, tw, lane);
    #pragma unroll
    for (int k1 = 0; k1 < 5; ++k1)
      tile[ri][k1 + 5*rv6] = A[k1];
  }
  __syncthreads();
  #pragma unroll
  for (int it = 0; it < 10; ++it) {
    const int idx = it * 256 + tid;
    const int u = idx >> 3;
    const int d = idx & 7;
    c32 val = tile[d][u];
    const size_t oidx = ((size_t)bc * NN + u) * NN + (r0 + d);
    if constexpr (OUT_MASK == 1) val = cscale(val, mask[oidx]);
    out[oidx] = val;
  }
}

// x0 = (lam/NN)*sum_c conj(sm)*img + z ; x=0, r=p=x0 ; fused final reduce -> x0x0, rr0, flag0
__global__ __launch_bounds__(256)
void init_combine(const c32* __restrict__ img, const c32* __restrict__ smaps,
                  const c32* __restrict__ z, c32* __restrict__ x,
                  c32* __restrict__ r, c32* __restrict__ p,
                  const float* __restrict__ lam, float* __restrict__ part,
                  float* __restrict__ x0x0, float* __restrict__ rr0,
                  float* __restrict__ flags, unsigned* __restrict__ cnt)
{
  const int b  = blockIdx.y;
  const int hw = blockIdx.x * 256 + threadIdx.x;
  const float l0 = lam[0] * (1.f / (float)NN);
  c32 a0 = make_float2(0.f,0.f), a1 = make_float2(0.f,0.f);
  #pragma unroll
  for (int c = 0; c < NC; ++c) {
    c32 iv = img[(size_t)(b*NC + c) * NHW + hw];
    c32 s0 = smaps[(size_t)((b*NC + c)*NM + 0) * NHW + hw];
    c32 s1 = smaps[(size_t)((b*NC + c)*NM + 1) * NHW + hw];
    a0 = cadd(a0, cmulj(s0, iv));
    a1 = cadd(a1, cmulj(s1, iv));
  }
  const size_t i0 = (size_t)(b*NM + 0) * NHW + hw;
  const size_t i1 = (size_t)(b*NM + 1) * NHW + hw;
  c32 x00 = cadd(cscale(a0, l0), z[i0]);
  c32 x01 = cadd(cscale(a1, l0), z[i1]);
  x[i0] = make_float2(0.f,0.f); x[i1] = make_float2(0.f,0.f);
  r[i0] = x00; r[i1] = x01;
  p[i0] = x00; p[i1] = x01;
  float acc = x00.x*x00.x + x00.y*x00.y + x01.x*x01.x + x01.y*x01.y;
  acc = wave_reduce_f(acc);
  __shared__ float sred[4];
  const int lane = threadIdx.x & 63, wv = threadIdx.x >> 6;
  if (lane == 0) sred[wv] = acc;
  __syncthreads();
  if (threadIdx.x == 0) part[b*CBLK + blockIdx.x] = sred[0]+sred[1]+sred[2]+sred[3];
  __threadfence();
  __shared__ int amLast;
  if (threadIdx.x == 0) amLast = (atomicAdd(cnt, 1u) == (unsigned)(NB*CBLK - 1));
  __syncthreads();
  if (amLast) {
    __threadfence();
    const int l2 = threadIdx.x & 63, w2 = threadIdx.x >> 6;  // w2 = b (NB==4)
    float s = 0.f;
    for (int j = l2; j < CBLK; j += 64) s += part[w2*CBLK + j];
    s = wave_reduce_f(s);
    if (l2 == 0) { x0x0[w2] = s; rr0[w2] = s; }
    if (threadIdx.x == 0) { flags[0] = 1.f; cnt[0] = 0u; }
  }
}

// q = (lam/NHW)*sum_c conj(sm)*img + p ; fused final reduce -> pq
__global__ __launch_bounds__(256)
void q_combine(const c32* __restrict__ img, const c32* __restrict__ smaps,
               const c32* __restrict__ p, c32* __restrict__ q,
               const float* __restrict__ lam, const float* __restrict__ flag,
               c32* __restrict__ pqpart, c32* __restrict__ pqout,
               unsigned* __restrict__ cnt)
{
  if (flag[0] == 0.f) return;
  const int b  = blockIdx.y;
  const int hw = blockIdx.x * 256 + threadIdx.x;
  const float lq = lam[0] * (1.f / (float)NHW);
  c32 a0 = make_float2(0.f,0.f), a1 = make_float2(0.f,0.f);
  #pragma unroll
  for (int c = 0; c < NC; ++c) {
    c32 iv = img[(size_t)(b*NC + c) * NHW + hw];
    c32 s0 = smaps[(size_t)((b*NC + c)*NM + 0) * NHW + hw];
    c32 s1 = smaps[(size_t)((b*NC + c)*NM + 1) * NHW + hw];
    a0 = cadd(a0, cmulj(s0, iv));
    a1 = cadd(a1, cmulj(s1, iv));
  }
  const size_t i0 = (size_t)(b*NM + 0) * NHW + hw;
  const size_t i1 = (size_t)(b*NM + 1) * NHW + hw;
  c32 p0 = p[i0], p1 = p[i1];
  c32 q0 = cadd(cscale(a0, lq), p0);
  c32 q1 = cadd(cscale(a1, lq), p1);
  q[i0] = q0; q[i1] = q1;
  c32 s = cadd(cmulj(q0, p0), cmulj(q1, p1));  // p*conj(q)
  s = wave_reduce_c(s);
  __shared__ c32 sred[4];
  const int lane = threadIdx.x & 63, wv = threadIdx.x >> 6;
  if (lane == 0) sred[wv] = s;
  __syncthreads();
  if (threadIdx.x == 0)
    pqpart[b*CBLK + blockIdx.x] = cadd(cadd(sred[0], sred[1]), cadd(sred[2], sred[3]));
  __threadfence();
  __shared__ int amLast;
  if (threadIdx.x == 0) amLast = (atomicAdd(cnt, 1u) == (unsigned)(NB*CBLK - 1));
  __syncthreads();
  if (amLast) {
    __threadfence();
    const int l2 = threadIdx.x & 63, w2 = threadIdx.x >> 6;
    c32 ss = make_float2(0.f, 0.f);
    for (int j = l2; j < CBLK; j += 64) ss = cadd(ss, pqpart[w2*CBLK + j]);
    ss = wave_reduce_c(ss);
    if (l2 == 0) pqout[w2] = ss;
    if (threadIdx.x == 0) cnt[0] = 0u;
  }
}

// alpha = rr*conj(pq)/|pq|^2 ; x += a p ; r -= a q ; fused reduce -> rr_new + next flag
__global__ __launch_bounds__(256)
void update1(c32* __restrict__ x, c32* __restrict__ r,
             const c32* __restrict__ p, const c32* __restrict__ q,
             const float* __restrict__ rr_i, const c32* __restrict__ pq_i,
             const float* __restrict__ flag_i, float* __restrict__ part,
             float* __restrict__ rr_n, const float* __restrict__ x0x0,
             float* __restrict__ flag_n, unsigned* __restrict__ cnt)
{
  if (flag_i[0] == 0.f) {
    if (blockIdx.x == 0 && blockIdx.y == 0) {
      if (threadIdx.x < NB) rr_n[threadIdx.x] = rr_i[threadIdx.x];
      if (threadIdx.x == 0) flag_n[0] = 0.f;
    }
    return;
  }
  const int b  = blockIdx.y;
  const int hw = blockIdx.x * 256 + threadIdx.x;
  const float rrv = rr_i[b];
  const c32 pqv = pq_i[b];
  const float den = pqv.x*pqv.x + pqv.y*pqv.y;
  const c32 alpha = make_float2(rrv * pqv.x / den, -rrv * pqv.y / den);
  float acc = 0.f;
  #pragma unroll
  for (int m = 0; m < NM; ++m) {
    const size_t idx = (size_t)(b*NM + m) * NHW + hw;
    c32 pe = p[idx], qe = q[idx];
    c32 xe = cadd(x[idx], cmul(alpha, pe));
    c32 re = csub(r[idx], cmul(alpha, qe));
    x[idx] = xe; r[idx] = re;
    acc += re.x*re.x + re.y*re.y;
  }
  acc = wave_reduce_f(acc);
  __shared__ float sred[4];
  const int lane = threadIdx.x & 63, wv = threadIdx.x >> 6;
  if (lane == 0) sred[wv] = acc;
  __syncthreads();
  if (threadIdx.x == 0) part[b*CBLK + blockIdx.x] = sred[0]+sred[1]+sred[2]+sred[3];
  __threadfence();
  __shared__ int amLast;
  if (threadIdx.x == 0) amLast = (atomicAdd(cnt, 1u) == (unsigned)(NB*CBLK - 1));
  __syncthreads();
  if (amLast) {
    __threadfence();
    const int l2 = threadIdx.x & 63, w2 = threadIdx.x >> 6;
    float s = 0.f;
    for (int j = l2; j < CBLK; j += 64) s += part[w2*CBLK + j];
    s = wave_reduce_f(s);
    __shared__ float srr[NB];
    if (l2 == 0) { rr_n[w2] = s; srr[w2] = s / x0x0[w2]; }
    __syncthreads();
    if (threadIdx.x == 0) {
      float mn = fminf(fminf(srr[0], srr[1]), fminf(srr[2], srr[3]));
      flag_n[0] = (mn > CG_TOL) ? 1.f : 0.f;
      cnt[0] = 0u;
    }
  }
}

// beta = rr_new / rr ; p = r + beta*p
__global__ __launch_bounds__(256)
void update2(c32* __restrict__ p, const c32* __restrict__ r,
             const float* __restrict__ rr_i, const float* __restrict__ rr_n,
             const float* __restrict__ flag)
{
  if (flag[0] == 0.f) return;
  const int b  = blockIdx.y;
  const int hw = blockIdx.x * 256 + threadIdx.x;
  const float beta = rr_n[b] / rr_i[b];
  #pragma unroll
  for (int m = 0; m < NM; ++m) {
    const size_t idx = (size_t)(b*NM + m) * NHW + hw;
    p[idx] = cadd(r[idx], cscale(p[idx], beta));
  }
}

extern "C" void kernel_launch(void* const* d_in, const int* in_sizes, int n_in,
                              void* d_out, int out_size, void* d_ws, size_t ws_size,
                              hipStream_t stream)
{
  const c32*  z   = (const c32*)d_in[0];   // x: (B,M,H,W,2)
  const c32*  y   = (const c32*)d_in[1];   // y: (B,C,H,W,2)
  const c32*  sm  = (const c32*)d_in[2];   // smaps: (B,C,M,H,W,2)
  const float* mk = (const float*)d_in[3]; // mask: (B,C,H,W,1)
  const float* lam= (const float*)d_in[4]; // lambda_a: (1,)
  c32* x = (c32*)d_out;

  char* base = (char*)d_ws;
  size_t off = 0;
  auto walloc = [&](size_t bytes) -> void* {
    void* ptr = base + off;
    off += (bytes + 255) & ~(size_t)255;
    return ptr;
  };
  c32* buf1   = (c32*)walloc((size_t)NBC * NHW * sizeof(c32));
  c32* buf2   = (c32*)walloc((size_t)NBC * NHW * sizeof(c32));
  c32* rv     = (c32*)walloc((size_t)NB * NM * NHW * sizeof(c32));
  c32* pv     = (c32*)walloc((size_t)NB * NM * NHW * sizeof(c32));
  c32* qv     = (c32*)walloc((size_t)NB * NM * NHW * sizeof(c32));
  c32* pqpart = (c32*)walloc((size_t)NB * CBLK * sizeof(c32));
  c32* pq     = (c32*)walloc((size_t)NITER * NB * sizeof(c32));
  float* x0x0 = (float*)walloc(NB * sizeof(float));
  float* rr   = (float*)walloc((NITER + 1) * NB * sizeof(float));
  float* flags= (float*)walloc((NITER + 1) * sizeof(float));
  float* part1= (float*)walloc((size_t)NB * CBLK * sizeof(float));
  c32* T320   = (c32*)walloc(256 * sizeof(c32));
  c32* T64    = (c32*)walloc(32 * sizeof(c32));
  unsigned* cnt = (unsigned*)walloc(8 * sizeof(unsigned));
  (void)ws_size; (void)in_sizes; (void)n_in; (void)out_size;

  dim3 fgrid(NN / 8, NBC), blk(256);
  dim3 cgrid(CBLK, NB);

  twiddle_init<<<1, 256, 0, stream>>>(T320, T64, cnt);

  // ---- setup: img(buf1) = unnormalized ifft2(y * mask) ----
  fft_pass<1, 2, 0><<<fgrid, blk, 0, stream>>>(y,    buf2, nullptr, nullptr, mk,      nullptr, T320, T64);
  fft_pass<1, 0, 0><<<fgrid, blk, 0, stream>>>(buf2, buf1, nullptr, nullptr, nullptr, nullptr, T320, T64);
  init_combine<<<cgrid, blk, 0, stream>>>(buf1, sm, z, x, rv, pv, lam, part1, x0x0, rr, flags, cnt + 0);

  // ---- 10 CG iterations ----
  for (int i = 0; i < NITER; ++i) {
    const float* fl = flags + i;
    fft_pass<-1, 1, 0><<<fgrid, blk, 0, stream>>>(nullptr, buf2, pv, sm, nullptr, fl, T320, T64);
    fft_pass<-1, 0, 1><<<fgrid, blk, 0, stream>>>(buf2, buf1, nullptr, nullptr, mk, fl, T320, T64);
    fft_pass< 1, 0, 0><<<fgrid, blk, 0, stream>>>(buf1, buf2, nullptr, nullptr, nullptr, fl, T320, T64);
    fft_pass< 1, 0, 0><<<fgrid, blk, 0, stream>>>(buf2, buf1, nullptr, nullptr, nullptr, fl, T320, T64);
    q_combine<<<cgrid, blk, 0, stream>>>(buf1, sm, pv, qv, lam, fl, pqpart, pq + i*NB, cnt + 1);
    update1<<<cgrid, blk, 0, stream>>>(x, rv, pv, qv, rr + i*NB, pq + i*NB, fl, part1,
                                       rr + (i+1)*NB, x0x0, flags + (i+1), cnt + 2);
    update2<<<cgrid, blk, 0, stream>>>(pv, rv, rr + i*NB, rr + (i+1)*NB, fl);
  }
}

// Round 3
// 430.780 us; speedup vs baseline: 3.2021x; 3.2021x over previous
//
#include <hip/hip_runtime.h>
#include <math.h>

#define NB 4
#define NC 12
#define NM 2
#define NN 320
#define NHW (NN*NN)
#define NBC (NB*NC)
#define CG_TOL 1e-6f
#define NITER 10
#define CBLK 400   // blocks per batch for combine/update kernels (102400/256)

#define TWO_PI_F 6.28318530717958647692f

typedef float2 c32;

__device__ __forceinline__ c32 cmul(c32 a, c32 b){ return make_float2(a.x*b.x - a.y*b.y, a.x*b.y + a.y*b.x); }
__device__ __forceinline__ c32 cmulj(c32 a, c32 b){ return make_float2(a.x*b.x + a.y*b.y, a.x*b.y - a.y*b.x); } // conj(a)*b
__device__ __forceinline__ c32 cadd(c32 a, c32 b){ return make_float2(a.x+b.x, a.y+b.y); }
__device__ __forceinline__ c32 csub(c32 a, c32 b){ return make_float2(a.x-b.x, a.y-b.y); }
__device__ __forceinline__ c32 cscale(c32 a, float s){ return make_float2(a.x*s, a.y*s); }

__device__ __forceinline__ float wave_reduce_f(float v) {
  #pragma unroll
  for (int off = 32; off >= 1; off >>= 1) v += __shfl_xor(v, off, 64);
  return v;
}
__device__ __forceinline__ c32 wave_reduce_c(c32 v) {
  #pragma unroll
  for (int off = 32; off >= 1; off >>= 1) {
    v.x += __shfl_xor(v.x, off, 64);
    v.y += __shfl_xor(v.y, off, 64);
  }
  return v;
}

// T320[j] = cis(2*pi*j/320), j=0..255 ; T64[k] = cis(2*pi*k/64), k=0..31.
__global__ __launch_bounds__(256)
void twiddle_init(c32* __restrict__ T320, c32* __restrict__ T64)
{
  const int t = threadIdx.x;
  {
    float s, c; sincosf(TWO_PI_F * (float)t / 320.f, &s, &c);
    T320[t] = make_float2(c, s);
  }
  if (t < 32) {
    float s, c; sincosf(TWO_PI_F * (float)t / 64.f, &s, &c);
    T64[t] = make_float2(c, s);
  }
}

// 320-point FFT: A[j] = x[64*j + lane]; output A[k1] at lane l = X[k1 + 5*rev6(l)].
// ct[4], tw[6] pre-signed for direction. Unnormalized.
template<int DIR>
__device__ __forceinline__ void fft320_tw(c32 A[5], const c32 ct[4], const c32 tw[6], int lane)
{
  constexpr float C72  = 0.30901699437494745f, S72  = 0.9510565162951535f;
  constexpr float C144 = -0.8090169943749475f, S144 = 0.5877852522924731f;
  const float sgn = (float)DIR;
  const c32 w51 = make_float2(C72,  sgn*S72);
  const c32 w52 = make_float2(C144, sgn*S144);
  const c32 w53 = make_float2(C144, -sgn*S144);
  const c32 w54 = make_float2(C72,  -sgn*S72);
  c32 v0=A[0], v1=A[1], v2=A[2], v3=A[3], v4=A[4];
  A[0] = cadd(cadd(v0, v1), cadd(cadd(v2, v3), v4));
  A[1] = cadd(v0, cadd(cadd(cmul(v1,w51), cmul(v2,w52)), cadd(cmul(v3,w53), cmul(v4,w54))));
  A[2] = cadd(v0, cadd(cadd(cmul(v1,w52), cmul(v2,w54)), cadd(cmul(v3,w51), cmul(v4,w53))));
  A[3] = cadd(v0, cadd(cadd(cmul(v1,w53), cmul(v2,w51)), cadd(cmul(v3,w54), cmul(v4,w52))));
  A[4] = cadd(v0, cadd(cadd(cmul(v1,w54), cmul(v2,w53)), cadd(cmul(v3,w52), cmul(v4,w51))));
  A[1] = cmul(A[1], ct[0]);
  A[2] = cmul(A[2], ct[1]);
  A[3] = cmul(A[3], ct[2]);
  A[4] = cmul(A[4], ct[3]);
  #pragma unroll
  for (int s = 0; s < 6; ++s) {
    const int m = 32 >> s;
    const c32 w = tw[s];
    const bool up = (lane & m) != 0;
    #pragma unroll
    for (int k1 = 0; k1 < 5; ++k1) {
      c32 o;
      o.x = __shfl_xor(A[k1].x, m, 64);
      o.y = __shfl_xor(A[k1].y, m, 64);
      c32 lo = cadd(A[k1], o);
      c32 hi = cmul(csub(o, A[k1]), w);
      A[k1] = up ? hi : lo;
    }
  }
}

// Batched 1D FFT over contiguous dim of (NBC, NN, NN).
// IN_MODE: 0 = in[]; 1 = sum_m p*sm on the fly; 2 = in[]*mask.
// OUT_MODE: 0 = transposed write; 1 = transposed write * mask; 2 = natural write.
template<int DIR, int IN_MODE, int OUT_MODE>
__global__ __launch_bounds__(256)
void fft_pass(const c32* __restrict__ in, c32* __restrict__ out,
              const c32* __restrict__ pvec, const c32* __restrict__ smaps,
              const float* __restrict__ mask, const float* __restrict__ flag,
              const c32* __restrict__ T320, const c32* __restrict__ T64)
{
  if (flag != nullptr && flag[0] == 0.f) return;
  __shared__ c32 tile[8][NN + 2];
  const int tid  = threadIdx.x;
  const int lane = tid & 63;
  const int wv   = tid >> 6;
  const int bc   = blockIdx.y;
  const int r0   = blockIdx.x * 8;
  const float sgn = (float)DIR;

  c32 ct[4], tw[6];
  #pragma unroll
  for (int k = 0; k < 4; ++k) {
    c32 t = T320[(k + 1) * lane];
    ct[k] = make_float2(t.x, sgn * t.y);
  }
  #pragma unroll
  for (int s = 0; s < 6; ++s) {
    const int m = 32 >> s;
    c32 t = T64[(lane & (m - 1)) << s];
    tw[s] = make_float2(t.x, sgn * t.y);
  }
  const int rv6 = __brev((unsigned)lane) >> 26;

  #pragma unroll
  for (int rep = 0; rep < 2; ++rep) {
    const int ri  = wv * 2 + rep;
    const int row = r0 + ri;
    c32 A[5];
    if constexpr (IN_MODE == 0) {
      #pragma unroll
      for (int j = 0; j < 5; ++j)
        A[j] = in[((size_t)bc * NN + row) * NN + lane + 64*j];
    } else if constexpr (IN_MODE == 1) {
      const int b = bc / NC;
      const int c = bc % NC;
      #pragma unroll
      for (int j = 0; j < 5; ++j) {
        const int col = lane + 64*j;
        const size_t hw = (size_t)row * NN + col;
        c32 p0 = pvec[(size_t)(b*NM + 0) * NHW + hw];
        c32 p1 = pvec[(size_t)(b*NM + 1) * NHW + hw];
        c32 s0 = smaps[(size_t)((b*NC + c)*NM + 0) * NHW + hw];
        c32 s1 = smaps[(size_t)((b*NC + c)*NM + 1) * NHW + hw];
        A[j] = cadd(cmul(p0, s0), cmul(p1, s1));
      }
    } else {
      #pragma unroll
      for (int j = 0; j < 5; ++j) {
        const size_t idx = ((size_t)bc * NN + row) * NN + lane + 64*j;
        A[j] = cscale(in[idx], mask[idx]);
      }
    }
    fft320_tw<DIR>(A, ct, tw, lane);
    #pragma unroll
    for (int k1 = 0; k1 < 5; ++k1)
      tile[ri][k1 + 5*rv6] = A[k1];
  }
  __syncthreads();
  if constexpr (OUT_MODE != 2) {
    #pragma unroll
    for (int it = 0; it < 10; ++it) {
      const int idx = it * 256 + tid;
      const int u = idx >> 3;
      const int d = idx & 7;
      c32 val = tile[d][u];
      const size_t oidx = ((size_t)bc * NN + u) * NN + (r0 + d);
      if constexpr (OUT_MODE == 1) val = cscale(val, mask[oidx]);
      out[oidx] = val;
    }
  } else {
    #pragma unroll
    for (int it = 0; it < 10; ++it) {
      const int idx = it * 256 + tid;
      const int d = idx / NN;
      const int u = idx - d * NN;
      out[((size_t)bc * NN + (r0 + d)) * NN + u] = tile[d][u];
    }
  }
}

// Fused k-space round trip along the contiguous dim (h):
// in (bc,u,h) -> FFT_h -> * mask[bc][k][u] -> IFFT_h -> transposed write out[bc][h][u].
__global__ __launch_bounds__(256)
void fft_mask_ifft(const c32* __restrict__ in, c32* __restrict__ out,
                   const float* __restrict__ mask, const float* __restrict__ flag,
                   const c32* __restrict__ T320, const c32* __restrict__ T64)
{
  if (flag[0] == 0.f) return;
  __shared__ c32 tile[8][NN + 2];
  const int tid  = threadIdx.x;
  const int lane = tid & 63;
  const int wv   = tid >> 6;
  const int bc   = blockIdx.y;
  const int r0   = blockIdx.x * 8;

  c32 ctf[4], twf[6], cti[4], twi[6];
  #pragma unroll
  for (int k = 0; k < 4; ++k) {
    c32 t = T320[(k + 1) * lane];
    ctf[k] = make_float2(t.x, -t.y);
    cti[k] = make_float2(t.x,  t.y);
  }
  #pragma unroll
  for (int s = 0; s < 6; ++s) {
    const int m = 32 >> s;
    c32 t = T64[(lane & (m - 1)) << s];
    twf[s] = make_float2(t.x, -t.y);
    twi[s] = make_float2(t.x,  t.y);
  }
  const int rv6 = __brev((unsigned)lane) >> 26;

  #pragma unroll
  for (int rep = 0; rep < 2; ++rep) {
    const int ri  = wv * 2 + rep;
    const int row = r0 + ri;         // row = u (k_w index)
    c32 A[5];
    #pragma unroll
    for (int j = 0; j < 5; ++j)
      A[j] = in[((size_t)bc * NN + row) * NN + lane + 64*j];
    fft320_tw<-1>(A, ctf, twf, lane);
    // mask in scrambled order: k_h = k1 + 5*rev6(lane)
    #pragma unroll
    for (int k1 = 0; k1 < 5; ++k1) {
      const int kh = k1 + 5*rv6;
      A[k1] = cscale(A[k1], mask[(size_t)bc * NHW + (size_t)kh * NN + row]);
    }
    // unscramble through own LDS rows (wave-local; no barrier needed)
    #pragma unroll
    for (int k1 = 0; k1 < 5; ++k1)
      tile[ri][k1 + 5*rv6] = A[k1];
    c32 Bv[5];
    #pragma unroll
    for (int j = 0; j < 5; ++j)
      Bv[j] = tile[ri][lane + 64*j];
    fft320_tw<1>(Bv, cti, twi, lane);
    #pragma unroll
    for (int k1 = 0; k1 < 5; ++k1)
      tile[ri][k1 + 5*rv6] = Bv[k1];
  }
  __syncthreads();
  #pragma unroll
  for (int it = 0; it < 10; ++it) {
    const int idx = it * 256 + tid;
    const int u = idx >> 3;          // image-h index
    const int d = idx & 7;
    out[((size_t)bc * NN + u) * NN + (r0 + d)] = tile[d][u];
  }
}

// x0 = (lam/NN)*sum_c conj(sm)*img + z ; x=0, r=p=x0 ; partial |x0|^2
__global__ __launch_bounds__(256)
void init_combine(const c32* __restrict__ img, const c32* __restrict__ smaps,
                  const c32* __restrict__ z, c32* __restrict__ x,
                  c32* __restrict__ r, c32* __restrict__ p,
                  const float* __restrict__ lam, float* __restrict__ part)
{
  const int b  = blockIdx.y;
  const int hw = blockIdx.x * 256 + threadIdx.x;
  const float l0 = lam[0] * (1.f / (float)NN);
  c32 a0 = make_float2(0.f,0.f), a1 = make_float2(0.f,0.f);
  #pragma unroll
  for (int c = 0; c < NC; ++c) {
    c32 iv = img[(size_t)(b*NC + c) * NHW + hw];
    c32 s0 = smaps[(size_t)((b*NC + c)*NM + 0) * NHW + hw];
    c32 s1 = smaps[(size_t)((b*NC + c)*NM + 1) * NHW + hw];
    a0 = cadd(a0, cmulj(s0, iv));
    a1 = cadd(a1, cmulj(s1, iv));
  }
  const size_t i0 = (size_t)(b*NM + 0) * NHW + hw;
  const size_t i1 = (size_t)(b*NM + 1) * NHW + hw;
  c32 x00 = cadd(cscale(a0, l0), z[i0]);
  c32 x01 = cadd(cscale(a1, l0), z[i1]);
  x[i0] = make_float2(0.f,0.f); x[i1] = make_float2(0.f,0.f);
  r[i0] = x00; r[i1] = x01;
  p[i0] = x00; p[i1] = x01;
  float acc = x00.x*x00.x + x00.y*x00.y + x01.x*x01.x + x01.y*x01.y;
  acc = wave_reduce_f(acc);
  __shared__ float sred[4];
  const int lane = threadIdx.x & 63, wv = threadIdx.x >> 6;
  if (lane == 0) sred[wv] = acc;
  __syncthreads();
  if (threadIdx.x == 0) part[b*CBLK + blockIdx.x] = sred[0]+sred[1]+sred[2]+sred[3];
}

__global__ void reduce_init(const float* __restrict__ part, float* __restrict__ x0x0,
                            float* __restrict__ rr0, float* __restrict__ flags)
{
  const int lane = threadIdx.x & 63;
  const int b = threadIdx.x >> 6;
  float s = 0.f;
  for (int j = lane; j < CBLK; j += 64) s += part[b*CBLK + j];
  s = wave_reduce_f(s);
  if (lane == 0) { x0x0[b] = s; rr0[b] = s; }
  if (threadIdx.x == 0) flags[0] = 1.f;
}

// q = (lam/NHW)*sum_c conj(sm)*img + p ; partial pq = sum p*conj(q)
__global__ __launch_bounds__(256)
void q_combine(const c32* __restrict__ img, const c32* __restrict__ smaps,
               const c32* __restrict__ p, c32* __restrict__ q,
               const float* __restrict__ lam, const float* __restrict__ flag,
               c32* __restrict__ pqpart)
{
  if (flag[0] == 0.f) return;
  const int b  = blockIdx.y;
  const int hw = blockIdx.x * 256 + threadIdx.x;
  const float lq = lam[0] * (1.f / (float)NHW);
  c32 a0 = make_float2(0.f,0.f), a1 = make_float2(0.f,0.f);
  #pragma unroll
  for (int c = 0; c < NC; ++c) {
    c32 iv = img[(size_t)(b*NC + c) * NHW + hw];
    c32 s0 = smaps[(size_t)((b*NC + c)*NM + 0) * NHW + hw];
    c32 s1 = smaps[(size_t)((b*NC + c)*NM + 1) * NHW + hw];
    a0 = cadd(a0, cmulj(s0, iv));
    a1 = cadd(a1, cmulj(s1, iv));
  }
  const size_t i0 = (size_t)(b*NM + 0) * NHW + hw;
  const size_t i1 = (size_t)(b*NM + 1) * NHW + hw;
  c32 p0 = p[i0], p1 = p[i1];
  c32 q0 = cadd(cscale(a0, lq), p0);
  c32 q1 = cadd(cscale(a1, lq), p1);
  q[i0] = q0; q[i1] = q1;
  c32 s = cadd(cmulj(q0, p0), cmulj(q1, p1));
  s = wave_reduce_c(s);
  __shared__ c32 sred[4];
  const int lane = threadIdx.x & 63, wv = threadIdx.x >> 6;
  if (lane == 0) sred[wv] = s;
  __syncthreads();
  if (threadIdx.x == 0)
    pqpart[b*CBLK + blockIdx.x] = cadd(cadd(sred[0], sred[1]), cadd(sred[2], sred[3]));
}

__global__ void reduce_pq(const c32* __restrict__ pqpart, c32* __restrict__ pqout,
                          const float* __restrict__ flag)
{
  if (flag[0] == 0.f) return;
  const int lane = threadIdx.x & 63;
  const int b = threadIdx.x >> 6;
  c32 s = make_float2(0.f, 0.f);
  for (int j = lane; j < CBLK; j += 64) s = cadd(s, pqpart[b*CBLK + j]);
  s = wave_reduce_c(s);
  if (lane == 0) pqout[b] = s;
}

// alpha = rr*conj(pq)/|pq|^2 ; x += a p ; r -= a q ; partial |r|^2
__global__ __launch_bounds__(256)
void update1(c32* __restrict__ x, c32* __restrict__ r,
             const c32* __restrict__ p, const c32* __restrict__ q,
             const float* __restrict__ rr_i, const c32* __restrict__ pq_i,
             const float* __restrict__ flag, float* __restrict__ part)
{
  if (flag[0] == 0.f) return;
  const int b  = blockIdx.y;
  const int hw = blockIdx.x * 256 + threadIdx.x;
  const float rrv = rr_i[b];
  const c32 pqv = pq_i[b];
  const float den = pqv.x*pqv.x + pqv.y*pqv.y;
  const c32 alpha = make_float2(rrv * pqv.x / den, -rrv * pqv.y / den);
  float acc = 0.f;
  #pragma unroll
  for (int m = 0; m < NM; ++m) {
    const size_t idx = (size_t)(b*NM + m) * NHW + hw;
    c32 pe = p[idx], qe = q[idx];
    c32 xe = cadd(x[idx], cmul(alpha, pe));
    c32 re = csub(r[idx], cmul(alpha, qe));
    x[idx] = xe; r[idx] = re;
    acc += re.x*re.x + re.y*re.y;
  }
  acc = wave_reduce_f(acc);
  __shared__ float sred[4];
  const int lane = threadIdx.x & 63, wv = threadIdx.x >> 6;
  if (lane == 0) sred[wv] = acc;
  __syncthreads();
  if (threadIdx.x == 0) part[b*CBLK + blockIdx.x] = sred[0]+sred[1]+sred[2]+sred[3];
}

__global__ void reduce_rr(const float* __restrict__ part, const float* __restrict__ rr_i,
                          float* __restrict__ rr_n, const float* __restrict__ x0x0,
                          const float* __restrict__ flag_i, float* __restrict__ flag_n)
{
  const int lane = threadIdx.x & 63;
  const int b = threadIdx.x >> 6;
  __shared__ float sred[4];
  __shared__ float sx0[4];
  if (flag_i[0] == 0.f) {
    if (lane == 0) rr_n[b] = rr_i[b];
    if (threadIdx.x == 0) flag_n[0] = 0.f;
    return;
  }
  float s = 0.f;
  for (int j = lane; j < CBLK; j += 64) s += part[b*CBLK + j];
  s = wave_reduce_f(s);
  if (lane == 0) { rr_n[b] = s; sred[b] = s; sx0[b] = x0x0[b]; }
  __syncthreads();
  if (threadIdx.x == 0) {
    float mn = 1e30f;
    #pragma unroll
    for (int bb = 0; bb < NB; ++bb) mn = fminf(mn, sred[bb] / sx0[bb]);
    flag_n[0] = (mn > CG_TOL) ? 1.f : 0.f;
  }
}

// beta = rr_new / rr ; p = r + beta*p
__global__ __launch_bounds__(256)
void update2(c32* __restrict__ p, const c32* __restrict__ r,
             const float* __restrict__ rr_i, const float* __restrict__ rr_n,
             const float* __restrict__ flag)
{
  if (flag[0] == 0.f) return;
  const int b  = blockIdx.y;
  const int hw = blockIdx.x * 256 + threadIdx.x;
  const float beta = rr_n[b] / rr_i[b];
  #pragma unroll
  for (int m = 0; m < NM; ++m) {
    const size_t idx = (size_t)(b*NM + m) * NHW + hw;
    p[idx] = cadd(r[idx], cscale(p[idx], beta));
  }
}

extern "C" void kernel_launch(void* const* d_in, const int* in_sizes, int n_in,
                              void* d_out, int out_size, void* d_ws, size_t ws_size,
                              hipStream_t stream)
{
  const c32*  z   = (const c32*)d_in[0];
  const c32*  y   = (const c32*)d_in[1];
  const c32*  sm  = (const c32*)d_in[2];
  const float* mk = (const float*)d_in[3];
  const float* lam= (const float*)d_in[4];
  c32* x = (c32*)d_out;

  char* base = (char*)d_ws;
  size_t off = 0;
  auto walloc = [&](size_t bytes) -> void* {
    void* ptr = base + off;
    off += (bytes + 255) & ~(size_t)255;
    return ptr;
  };
  c32* buf1   = (c32*)walloc((size_t)NBC * NHW * sizeof(c32));
  c32* buf2   = (c32*)walloc((size_t)NBC * NHW * sizeof(c32));
  c32* rv     = (c32*)walloc((size_t)NB * NM * NHW * sizeof(c32));
  c32* pv     = (c32*)walloc((size_t)NB * NM * NHW * sizeof(c32));
  c32* qv     = (c32*)walloc((size_t)NB * NM * NHW * sizeof(c32));
  c32* pqpart = (c32*)walloc((size_t)NB * CBLK * sizeof(c32));
  c32* pq     = (c32*)walloc((size_t)NITER * NB * sizeof(c32));
  float* x0x0 = (float*)walloc(NB * sizeof(float));
  float* rr   = (float*)walloc((NITER + 1) * NB * sizeof(float));
  float* flags= (float*)walloc((NITER + 1) * sizeof(float));
  float* part1= (float*)walloc((size_t)NB * CBLK * sizeof(float));
  c32* T320   = (c32*)walloc(256 * sizeof(c32));
  c32* T64    = (c32*)walloc(32 * sizeof(c32));
  (void)ws_size; (void)in_sizes; (void)n_in; (void)out_size;

  dim3 fgrid(NN / 8, NBC), blk(256);
  dim3 cgrid(CBLK, NB);

  twiddle_init<<<1, 256, 0, stream>>>(T320, T64);

  // ---- setup: img(buf1) = unnormalized ifft2(y * mask) ----
  fft_pass<1, 2, 0><<<fgrid, blk, 0, stream>>>(y,    buf2, nullptr, nullptr, mk,      nullptr, T320, T64);
  fft_pass<1, 0, 0><<<fgrid, blk, 0, stream>>>(buf2, buf1, nullptr, nullptr, nullptr, nullptr, T320, T64);
  init_combine<<<cgrid, blk, 0, stream>>>(buf1, sm, z, x, rv, pv, lam, part1);
  reduce_init<<<1, 256, 0, stream>>>(part1, x0x0, rr, flags);

  // ---- 10 CG iterations ----
  for (int i = 0; i < NITER; ++i) {
    const float* fl = flags + i;
    // Mop(p): FFT_w -> [FFT_h -> mask -> IFFT_h] -> IFFT_w
    fft_pass<-1, 1, 0><<<fgrid, blk, 0, stream>>>(nullptr, buf2, pv, sm, nullptr, fl, T320, T64);
    fft_mask_ifft<<<fgrid, blk, 0, stream>>>(buf2, buf1, mk, fl, T320, T64);
    fft_pass<1, 0, 2><<<fgrid, blk, 0, stream>>>(buf1, buf2, nullptr, nullptr, nullptr, fl, T320, T64);
    q_combine<<<cgrid, blk, 0, stream>>>(buf2, sm, pv, qv, lam, fl, pqpart);
    reduce_pq<<<1, 256, 0, stream>>>(pqpart, pq + i*NB, fl);
    update1<<<cgrid, blk, 0, stream>>>(x, rv, pv, qv, rr + i*NB, pq + i*NB, fl, part1);
    reduce_rr<<<1, 256, 0, stream>>>(part1, rr + i*NB, rr + (i+1)*NB, x0x0, fl, flags + (i+1));
    update2<<<cgrid, blk, 0, stream>>>(pv, rv, rr + i*NB, rr + (i+1)*NB, fl);
  }
}

// Round 4
// 398.859 us; speedup vs baseline: 3.4583x; 1.0800x over previous
//
#include <hip/hip_runtime.h>
#include <math.h>

#define NB 4
#define NC 12
#define NM 2
#define NN 320
#define NHW (NN*NN)
#define NBC (NB*NC)
#define CG_TOL 1e-6f
#define NITER 10
#define CBLK 400   // blocks per batch for combine/update kernels (102400/256)

#define TWO_PI_F 6.28318530717958647692f

typedef float2 c32;

__device__ __forceinline__ c32 cmul(c32 a, c32 b){ return make_float2(a.x*b.x - a.y*b.y, a.x*b.y + a.y*b.x); }
__device__ __forceinline__ c32 cmulj(c32 a, c32 b){ return make_float2(a.x*b.x + a.y*b.y, a.x*b.y - a.y*b.x); } // conj(a)*b
__device__ __forceinline__ c32 cadd(c32 a, c32 b){ return make_float2(a.x+b.x, a.y+b.y); }
__device__ __forceinline__ c32 csub(c32 a, c32 b){ return make_float2(a.x-b.x, a.y-b.y); }
__device__ __forceinline__ c32 cscale(c32 a, float s){ return make_float2(a.x*s, a.y*s); }

// multiply a by (FWD ? conj(t) : t) — lets fwd/inv share one twiddle table
template<bool FWD>
__device__ __forceinline__ c32 twmul(c32 a, c32 t){
  return FWD ? make_float2(a.x*t.x + a.y*t.y, a.y*t.x - a.x*t.y)
             : make_float2(a.x*t.x - a.y*t.y, a.y*t.x + a.x*t.y);
}

__device__ __forceinline__ float wave_reduce_f(float v) {
  #pragma unroll
  for (int off = 32; off >= 1; off >>= 1) v += __shfl_xor(v, off, 64);
  return v;
}
__device__ __forceinline__ c32 wave_reduce_c(c32 v) {
  #pragma unroll
  for (int off = 32; off >= 1; off >>= 1) {
    v.x += __shfl_xor(v.x, off, 64);
    v.y += __shfl_xor(v.y, off, 64);
  }
  return v;
}

// T320[j] = cis(2*pi*j/320), j=0..255 ; T64[k] = cis(2*pi*k/64), k=0..31.
__global__ __launch_bounds__(256)
void twiddle_init(c32* __restrict__ T320, c32* __restrict__ T64)
{
  const int t = threadIdx.x;
  {
    float s, c; sincosf(TWO_PI_F * (float)t / 320.f, &s, &c);
    T320[t] = make_float2(c, s);
  }
  if (t < 32) {
    float s, c; sincosf(TWO_PI_F * (float)t / 64.f, &s, &c);
    T64[t] = make_float2(c, s);
  }
}

template<bool FWD>
__device__ __forceinline__ void radix5(c32 V[5]) {
  constexpr float C1 = 0.30901699437494745f;   // cos 72
  constexpr float S1 = 0.9510565162951535f;    // sin 72
  constexpr float C2 = -0.8090169943749475f;   // cos 144
  constexpr float S2 = 0.5877852522924731f;    // sin 144
  constexpr float sg = FWD ? -1.f : 1.f;
  const c32 w1 = make_float2(C1,  sg*S1);
  const c32 w2 = make_float2(C2,  sg*S2);
  const c32 w3 = make_float2(C2, -sg*S2);
  const c32 w4 = make_float2(C1, -sg*S1);
  c32 v0=V[0], v1=V[1], v2=V[2], v3=V[3], v4=V[4];
  V[0] = cadd(cadd(v0, v1), cadd(cadd(v2, v3), v4));
  V[1] = cadd(v0, cadd(cadd(cmul(v1,w1), cmul(v2,w2)), cadd(cmul(v3,w3), cmul(v4,w4))));
  V[2] = cadd(v0, cadd(cadd(cmul(v1,w2), cmul(v2,w4)), cadd(cmul(v3,w1), cmul(v4,w3))));
  V[3] = cadd(v0, cadd(cadd(cmul(v1,w3), cmul(v2,w1)), cadd(cmul(v3,w4), cmul(v4,w2))));
  V[4] = cadd(v0, cadd(cadd(cmul(v1,w4), cmul(v2,w3)), cadd(cmul(v3,w2), cmul(v4,w1))));
}

// Two interleaved 320-pt FFTs (rows A and B) for 2x ILP on the shfl chain.
// Input A[j]=x[64j+lane]; output A[k1] at lane l = X[k1+5*rev6(l)]. Unnormalized.
template<bool FWD>
__device__ __forceinline__ void fft320_x2(c32 A[5], c32 B[5],
                                          const c32 ct[4], const c32 tw[6], int lane)
{
  radix5<FWD>(A);
  radix5<FWD>(B);
  #pragma unroll
  for (int k = 1; k < 5; ++k) {
    A[k] = twmul<FWD>(A[k], ct[k-1]);
    B[k] = twmul<FWD>(B[k], ct[k-1]);
  }
  #pragma unroll
  for (int s = 0; s < 6; ++s) {
    const int m = 32 >> s;
    const c32 w = tw[s];
    const bool up = (lane & m) != 0;
    c32 oA[5], oB[5];
    #pragma unroll
    for (int k = 0; k < 5; ++k) { oA[k].x = __shfl_xor(A[k].x, m, 64); oA[k].y = __shfl_xor(A[k].y, m, 64); }
    #pragma unroll
    for (int k = 0; k < 5; ++k) { oB[k].x = __shfl_xor(B[k].x, m, 64); oB[k].y = __shfl_xor(B[k].y, m, 64); }
    #pragma unroll
    for (int k = 0; k < 5; ++k) {
      c32 loA = cadd(A[k], oA[k]);
      c32 hiA = twmul<FWD>(csub(oA[k], A[k]), w);
      A[k] = up ? hiA : loA;
      c32 loB = cadd(B[k], oB[k]);
      c32 hiB = twmul<FWD>(csub(oB[k], B[k]), w);
      B[k] = up ? hiB : loB;
    }
  }
}

#define LOAD_TWIDDLES \
  c32 ct[4], tw[6]; \
  _Pragma("unroll") for (int k_ = 0; k_ < 4; ++k_) ct[k_] = T320[(k_ + 1) * lane]; \
  _Pragma("unroll") for (int s_ = 0; s_ < 6; ++s_) tw[s_] = T64[(lane & ((32 >> s_) - 1)) << s_];

// Batched 1D FFT over contiguous dim of (NBC, NN, NN).
// MASK_IN: multiply input by mask. NAT_OUT: natural-layout write (else transposed).
template<bool FWD, bool MASK_IN, bool NAT_OUT>
__global__ __launch_bounds__(256)
void fft_pass(const c32* __restrict__ in, c32* __restrict__ out,
              const float* __restrict__ mask, const float* __restrict__ flag,
              const c32* __restrict__ T320, const c32* __restrict__ T64)
{
  if (flag != nullptr && flag[0] == 0.f) return;
  __shared__ c32 tile[8][NN + 2];
  const int tid = threadIdx.x, lane = tid & 63, wv = tid >> 6;
  const int bc = blockIdx.y, r0 = blockIdx.x * 8;
  LOAD_TWIDDLES
  const int rv6 = __brev((unsigned)lane) >> 26;
  const int rA = r0 + wv*2, rB = rA + 1;
  c32 A[5], B[5];
  #pragma unroll
  for (int j = 0; j < 5; ++j) {
    const size_t iA = ((size_t)bc * NN + rA) * NN + lane + 64*j;
    const size_t iB = ((size_t)bc * NN + rB) * NN + lane + 64*j;
    A[j] = in[iA]; B[j] = in[iB];
    if constexpr (MASK_IN) { A[j] = cscale(A[j], mask[iA]); B[j] = cscale(B[j], mask[iB]); }
  }
  fft320_x2<FWD>(A, B, ct, tw, lane);
  #pragma unroll
  for (int k = 0; k < 5; ++k) {
    tile[wv*2    ][k + 5*rv6] = A[k];
    tile[wv*2 + 1][k + 5*rv6] = B[k];
  }
  __syncthreads();
  if constexpr (!NAT_OUT) {
    #pragma unroll
    for (int it = 0; it < 10; ++it) {
      const int idx = it * 256 + tid, u = idx >> 3, d = idx & 7;
      out[((size_t)bc * NN + u) * NN + (r0 + d)] = tile[d][u];
    }
  } else {
    #pragma unroll
    for (int it = 0; it < 10; ++it) {
      const int idx = it * 256 + tid, d = idx / NN, u = idx - d * NN;
      out[((size_t)bc * NN + (r0 + d)) * NN + u] = tile[d][u];
    }
  }
}

// Fused: p_new = r + beta*p_prev (beta = rr_cur/rr_prev; identity at iter 0),
// coil-combine sum_m p_new*sm, forward FFT_w, transposed write.
// Blocks with c==0 persist p_new into pout (ping-pong: pout != pin, no race).
__global__ __launch_bounds__(256)
void fft_comb(c32* __restrict__ out, const c32* __restrict__ pin,
              const c32* __restrict__ rres, c32* __restrict__ pout,
              const c32* __restrict__ smaps,
              const float* __restrict__ rr_prev, const float* __restrict__ rr_cur,
              const float* __restrict__ flag,
              const c32* __restrict__ T320, const c32* __restrict__ T64)
{
  if (flag[0] == 0.f) return;
  __shared__ c32 tile[8][NN + 2];
  const int tid = threadIdx.x, lane = tid & 63, wv = tid >> 6;
  const int bc = blockIdx.y, r0 = blockIdx.x * 8;
  const int b = bc / NC, c = bc - b * NC;
  const bool upd = (rr_cur != nullptr);
  const float beta = upd ? rr_cur[b] / rr_prev[b] : 0.f;
  LOAD_TWIDDLES
  const int rv6 = __brev((unsigned)lane) >> 26;
  const int rA = r0 + wv*2, rB = rA + 1;
  const size_t m0 = (size_t)(b*NM + 0) * NHW, m1 = (size_t)(b*NM + 1) * NHW;
  const size_t s0o = (size_t)((b*NC + c)*NM + 0) * NHW, s1o = (size_t)((b*NC + c)*NM + 1) * NHW;
  c32 A[5], B[5];
  #pragma unroll
  for (int j = 0; j < 5; ++j) {
    const size_t hA = (size_t)rA * NN + lane + 64*j;
    const size_t hB = (size_t)rB * NN + lane + 64*j;
    c32 r0A = rres[m0 + hA], r1A = rres[m1 + hA];
    c32 r0B = rres[m0 + hB], r1B = rres[m1 + hB];
    c32 p0A, p1A, p0B, p1B;
    if (upd) {
      p0A = cadd(r0A, cscale(pin[m0 + hA], beta));
      p1A = cadd(r1A, cscale(pin[m1 + hA], beta));
      p0B = cadd(r0B, cscale(pin[m0 + hB], beta));
      p1B = cadd(r1B, cscale(pin[m1 + hB], beta));
      if (c == 0) {
        pout[m0 + hA] = p0A; pout[m1 + hA] = p1A;
        pout[m0 + hB] = p0B; pout[m1 + hB] = p1B;
      }
    } else {
      p0A = r0A; p1A = r1A; p0B = r0B; p1B = r1B;   // iter 0: p = r = x0
    }
    A[j] = cadd(cmul(p0A, smaps[s0o + hA]), cmul(p1A, smaps[s1o + hA]));
    B[j] = cadd(cmul(p0B, smaps[s0o + hB]), cmul(p1B, smaps[s1o + hB]));
  }
  fft320_x2<true>(A, B, ct, tw, lane);
  #pragma unroll
  for (int k = 0; k < 5; ++k) {
    tile[wv*2    ][k + 5*rv6] = A[k];
    tile[wv*2 + 1][k + 5*rv6] = B[k];
  }
  __syncthreads();
  #pragma unroll
  for (int it = 0; it < 10; ++it) {
    const int idx = it * 256 + tid, u = idx >> 3, d = idx & 7;
    out[((size_t)bc * NN + u) * NN + (r0 + d)] = tile[d][u];
  }
}

// Fused k-space round trip along contiguous dim: FFT_h -> *mask -> IFFT_h -> transposed write.
__global__ __launch_bounds__(256)
void fft_mask_ifft(const c32* __restrict__ in, c32* __restrict__ out,
                   const float* __restrict__ mask, const float* __restrict__ flag,
                   const c32* __restrict__ T320, const c32* __restrict__ T64)
{
  if (flag[0] == 0.f) return;
  __shared__ c32 tile[8][NN + 2];
  const int tid = threadIdx.x, lane = tid & 63, wv = tid >> 6;
  const int bc = blockIdx.y, r0 = blockIdx.x * 8;
  LOAD_TWIDDLES
  const int rv6 = __brev((unsigned)lane) >> 26;
  const int rA = r0 + wv*2, rB = rA + 1;
  c32 A[5], B[5];
  #pragma unroll
  for (int j = 0; j < 5; ++j) {
    A[j] = in[((size_t)bc * NN + rA) * NN + lane + 64*j];
    B[j] = in[((size_t)bc * NN + rB) * NN + lane + 64*j];
  }
  fft320_x2<true>(A, B, ct, tw, lane);
  // mask in scrambled order: k_h = k1 + 5*rev6(lane); row index = k_w
  #pragma unroll
  for (int k = 0; k < 5; ++k) {
    const int kh = k + 5*rv6;
    A[k] = cscale(A[k], mask[(size_t)bc * NHW + (size_t)kh * NN + rA]);
    B[k] = cscale(B[k], mask[(size_t)bc * NHW + (size_t)kh * NN + rB]);
  }
  // unscramble through wave-owned LDS rows (in-wave DS ordering; no barrier)
  #pragma unroll
  for (int k = 0; k < 5; ++k) {
    tile[wv*2    ][k + 5*rv6] = A[k];
    tile[wv*2 + 1][k + 5*rv6] = B[k];
  }
  #pragma unroll
  for (int j = 0; j < 5; ++j) {
    A[j] = tile[wv*2    ][lane + 64*j];
    B[j] = tile[wv*2 + 1][lane + 64*j];
  }
  fft320_x2<false>(A, B, ct, tw, lane);
  #pragma unroll
  for (int k = 0; k < 5; ++k) {
    tile[wv*2    ][k + 5*rv6] = A[k];
    tile[wv*2 + 1][k + 5*rv6] = B[k];
  }
  __syncthreads();
  #pragma unroll
  for (int it = 0; it < 10; ++it) {
    const int idx = it * 256 + tid, u = idx >> 3, d = idx & 7;
    out[((size_t)bc * NN + u) * NN + (r0 + d)] = tile[d][u];
  }
}

// x0 = (lam/NN)*sum_c conj(sm)*img + z ; x=0, r=p=x0 ; partial |x0|^2
__global__ __launch_bounds__(256)
void init_combine(const c32* __restrict__ img, const c32* __restrict__ smaps,
                  const c32* __restrict__ z, c32* __restrict__ x,
                  c32* __restrict__ r, c32* __restrict__ p,
                  const float* __restrict__ lam, float* __restrict__ part)
{
  const int b  = blockIdx.y;
  const int hw = blockIdx.x * 256 + threadIdx.x;
  const float l0 = lam[0] * (1.f / (float)NN);
  c32 a0 = make_float2(0.f,0.f), a1 = make_float2(0.f,0.f);
  #pragma unroll
  for (int c = 0; c < NC; ++c) {
    c32 iv = img[(size_t)(b*NC + c) * NHW + hw];
    c32 s0 = smaps[(size_t)((b*NC + c)*NM + 0) * NHW + hw];
    c32 s1 = smaps[(size_t)((b*NC + c)*NM + 1) * NHW + hw];
    a0 = cadd(a0, cmulj(s0, iv));
    a1 = cadd(a1, cmulj(s1, iv));
  }
  const size_t i0 = (size_t)(b*NM + 0) * NHW + hw;
  const size_t i1 = (size_t)(b*NM + 1) * NHW + hw;
  c32 x00 = cadd(cscale(a0, l0), z[i0]);
  c32 x01 = cadd(cscale(a1, l0), z[i1]);
  x[i0] = make_float2(0.f,0.f); x[i1] = make_float2(0.f,0.f);
  r[i0] = x00; r[i1] = x01;
  p[i0] = x00; p[i1] = x01;
  float acc = x00.x*x00.x + x00.y*x00.y + x01.x*x01.x + x01.y*x01.y;
  acc = wave_reduce_f(acc);
  __shared__ float sred[4];
  const int lane = threadIdx.x & 63, wv = threadIdx.x >> 6;
  if (lane == 0) sred[wv] = acc;
  __syncthreads();
  if (threadIdx.x == 0) part[b*CBLK + blockIdx.x] = sred[0]+sred[1]+sred[2]+sred[3];
}

__global__ void reduce_init(const float* __restrict__ part, float* __restrict__ x0x0,
                            float* __restrict__ rr0, float* __restrict__ flags)
{
  const int lane = threadIdx.x & 63;
  const int b = threadIdx.x >> 6;
  float s = 0.f;
  for (int j = lane; j < CBLK; j += 64) s += part[b*CBLK + j];
  s = wave_reduce_f(s);
  if (lane == 0) { x0x0[b] = s; rr0[b] = s; }
  if (threadIdx.x == 0) flags[0] = 1.f;
}

// q = (lam/NHW)*sum_c conj(sm)*img + p ; per-block pq partials
__global__ __launch_bounds__(256)
void q_combine(const c32* __restrict__ img, const c32* __restrict__ smaps,
               const c32* __restrict__ p, c32* __restrict__ q,
               const float* __restrict__ lam, const float* __restrict__ flag,
               c32* __restrict__ pqpart)
{
  if (flag[0] == 0.f) return;
  const int b  = blockIdx.y;
  const int hw = blockIdx.x * 256 + threadIdx.x;
  const float lq = lam[0] * (1.f / (float)NHW);
  c32 a0 = make_float2(0.f,0.f), a1 = make_float2(0.f,0.f);
  #pragma unroll
  for (int c = 0; c < NC; ++c) {
    c32 iv = img[(size_t)(b*NC + c) * NHW + hw];
    c32 s0 = smaps[(size_t)((b*NC + c)*NM + 0) * NHW + hw];
    c32 s1 = smaps[(size_t)((b*NC + c)*NM + 1) * NHW + hw];
    a0 = cadd(a0, cmulj(s0, iv));
    a1 = cadd(a1, cmulj(s1, iv));
  }
  const size_t i0 = (size_t)(b*NM + 0) * NHW + hw;
  const size_t i1 = (size_t)(b*NM + 1) * NHW + hw;
  c32 p0 = p[i0], p1 = p[i1];
  c32 q0 = cadd(cscale(a0, lq), p0);
  c32 q1 = cadd(cscale(a1, lq), p1);
  q[i0] = q0; q[i1] = q1;
  c32 s = cadd(cmulj(q0, p0), cmulj(q1, p1));
  s = wave_reduce_c(s);
  __shared__ c32 sred[4];
  const int lane = threadIdx.x & 63, wv = threadIdx.x >> 6;
  if (lane == 0) sred[wv] = s;
  __syncthreads();
  if (threadIdx.x == 0)
    pqpart[b*CBLK + blockIdx.x] = cadd(cadd(sred[0], sred[1]), cadd(sred[2], sred[3]));
}

// Per-block pq re-reduction (deterministic, L2-resident) -> alpha; x += a p; r -= a q; |r|^2 partials
__global__ __launch_bounds__(256)
void update1(c32* __restrict__ x, c32* __restrict__ r,
             const c32* __restrict__ p, const c32* __restrict__ q,
             const float* __restrict__ rr_i, const c32* __restrict__ pqpart,
             const float* __restrict__ flag, float* __restrict__ part)
{
  if (flag[0] == 0.f) return;
  const int b = blockIdx.y;
  const int t = threadIdx.x;
  c32 s = make_float2(0.f, 0.f);
  for (int j = t; j < CBLK; j += 256) s = cadd(s, pqpart[b*CBLK + j]);
  s = wave_reduce_c(s);
  __shared__ c32 spq[4];
  const int lane = t & 63, wv = t >> 6;
  if (lane == 0) spq[wv] = s;
  __syncthreads();
  const c32 pqv = cadd(cadd(spq[0], spq[1]), cadd(spq[2], spq[3]));
  const float rrv = rr_i[b];
  const float den = pqv.x*pqv.x + pqv.y*pqv.y;
  const c32 alpha = make_float2(rrv * pqv.x / den, -rrv * pqv.y / den);
  const int hw = blockIdx.x * 256 + t;
  float acc = 0.f;
  #pragma unroll
  for (int m = 0; m < NM; ++m) {
    const size_t idx = (size_t)(b*NM + m) * NHW + hw;
    c32 pe = p[idx], qe = q[idx];
    c32 xe = cadd(x[idx], cmul(alpha, pe));
    c32 re = csub(r[idx], cmul(alpha, qe));
    x[idx] = xe; r[idx] = re;
    acc += re.x*re.x + re.y*re.y;
  }
  acc = wave_reduce_f(acc);
  __shared__ float sred[4];
  if (lane == 0) sred[wv] = acc;
  __syncthreads();
  if (t == 0) part[b*CBLK + blockIdx.x] = sred[0]+sred[1]+sred[2]+sred[3];
}

__global__ void reduce_rr(const float* __restrict__ part, const float* __restrict__ rr_i,
                          float* __restrict__ rr_n, const float* __restrict__ x0x0,
                          const float* __restrict__ flag_i, float* __restrict__ flag_n)
{
  const int lane = threadIdx.x & 63;
  const int b = threadIdx.x >> 6;
  __shared__ float sred[4];
  __shared__ float sx0[4];
  if (flag_i[0] == 0.f) {
    if (lane == 0) rr_n[b] = rr_i[b];
    if (threadIdx.x == 0) flag_n[0] = 0.f;
    return;
  }
  float s = 0.f;
  for (int j = lane; j < CBLK; j += 64) s += part[b*CBLK + j];
  s = wave_reduce_f(s);
  if (lane == 0) { rr_n[b] = s; sred[b] = s; sx0[b] = x0x0[b]; }
  __syncthreads();
  if (threadIdx.x == 0) {
    float mn = 1e30f;
    #pragma unroll
    for (int bb = 0; bb < NB; ++bb) mn = fminf(mn, sred[bb] / sx0[bb]);
    flag_n[0] = (mn > CG_TOL) ? 1.f : 0.f;
  }
}

extern "C" void kernel_launch(void* const* d_in, const int* in_sizes, int n_in,
                              void* d_out, int out_size, void* d_ws, size_t ws_size,
                              hipStream_t stream)
{
  const c32*  z   = (const c32*)d_in[0];
  const c32*  y   = (const c32*)d_in[1];
  const c32*  sm  = (const c32*)d_in[2];
  const float* mk = (const float*)d_in[3];
  const float* lam= (const float*)d_in[4];
  c32* x = (c32*)d_out;

  char* base = (char*)d_ws;
  size_t off = 0;
  auto walloc = [&](size_t bytes) -> void* {
    void* ptr = base + off;
    off += (bytes + 255) & ~(size_t)255;
    return ptr;
  };
  c32* buf1   = (c32*)walloc((size_t)NBC * NHW * sizeof(c32));
  c32* buf2   = (c32*)walloc((size_t)NBC * NHW * sizeof(c32));
  c32* rv     = (c32*)walloc((size_t)NB * NM * NHW * sizeof(c32));
  c32* pvA    = (c32*)walloc((size_t)NB * NM * NHW * sizeof(c32));
  c32* pvB    = (c32*)walloc((size_t)NB * NM * NHW * sizeof(c32));
  c32* qv     = (c32*)walloc((size_t)NB * NM * NHW * sizeof(c32));
  c32* pqpart = (c32*)walloc((size_t)NB * CBLK * sizeof(c32));
  float* x0x0 = (float*)walloc(NB * sizeof(float));
  float* rr   = (float*)walloc((NITER + 1) * NB * sizeof(float));
  float* flags= (float*)walloc((NITER + 1) * sizeof(float));
  float* part1= (float*)walloc((size_t)NB * CBLK * sizeof(float));
  c32* T320   = (c32*)walloc(256 * sizeof(c32));
  c32* T64    = (c32*)walloc(32 * sizeof(c32));
  (void)ws_size; (void)in_sizes; (void)n_in; (void)out_size;

  dim3 fgrid(NN / 8, NBC), blk(256);
  dim3 cgrid(CBLK, NB);

  twiddle_init<<<1, 256, 0, stream>>>(T320, T64);

  // ---- setup: img(buf1) = unnormalized ifft2(y * mask) ----
  fft_pass<false, true,  false><<<fgrid, blk, 0, stream>>>(y,    buf2, mk,      nullptr, T320, T64);
  fft_pass<false, false, false><<<fgrid, blk, 0, stream>>>(buf2, buf1, nullptr, nullptr, T320, T64);
  init_combine<<<cgrid, blk, 0, stream>>>(buf1, sm, z, x, rv, pvA, lam, part1);
  reduce_init<<<1, 256, 0, stream>>>(part1, x0x0, rr, flags);

  // ---- 10 CG iterations (6 kernels each) ----
  for (int i = 0; i < NITER; ++i) {
    const float* fl = flags + i;
    c32* pin  = (i & 1) ? pvA : pvB;        // unused at i==0 (upd=false)
    c32* pout = (i & 1) ? pvB : pvA;        // i=0: pvA (holds x0, not rewritten)
    const float* rrprev = (i > 0) ? (rr + (i-1)*NB) : rr;
    const float* rrcur  = (i > 0) ? (rr + i*NB) : nullptr;
    fft_comb<<<fgrid, blk, 0, stream>>>(buf2, pin, rv, pout, sm, rrprev, rrcur, fl, T320, T64);
    fft_mask_ifft<<<fgrid, blk, 0, stream>>>(buf2, buf1, mk, fl, T320, T64);
    fft_pass<false, false, true><<<fgrid, blk, 0, stream>>>(buf1, buf2, nullptr, fl, T320, T64);
    q_combine<<<cgrid, blk, 0, stream>>>(buf2, sm, pout, qv, lam, fl, pqpart);
    update1<<<cgrid, blk, 0, stream>>>(x, rv, pout, qv, rr + i*NB, pqpart, fl, part1);
    reduce_rr<<<1, 256, 0, stream>>>(part1, rr + i*NB, rr + (i+1)*NB, x0x0, fl, flags + (i+1));
  }
}